// Round 1
// baseline (177.202 us; speedup 1.0000x reference)
//
#include <hip/hip_runtime.h>

#define B_SZ 128
#define MCHK 288
#define NVAR 576
#define KINFO 288
#define NITER 5
#define CAP 40      // max edges per check row (mean 11.5, 8.5 sigma headroom)
#define LCAP 3712   // max edges per batch element (mean 3318, 6.9 sigma)
#define TPB 1024

// ---------------------------------------------------------------------------
// Fused kernel: one 1024-thread block per batch element.
//  Phase A: scan this batch's H slice (float4, all 16 waves), build per-row
//           edge index lists directly in LDS (staged over the Mld/tld region,
//           which is not live yet). Same per-lane emission order as the old
//           build_edges kernel -> identical edge order -> identical rounding.
//  Phase B: shfl-based scan of the 288 row counts (2 barriers instead of the
//           old 18-barrier Hillis-Steele), compact into the packed ev[] list.
//  Phase C: 5 BP iterations, numerically identical to the previous kernel.
// No global workspace, single launch.
// ---------------------------------------------------------------------------
__global__ __launch_bounds__(TPB) void decode(
    const float* __restrict__ inp,   const float* __restrict__ H,
    const float* __restrict__ sigma2,
    const float* __restrict__ ipond, const float* __restrict__ opond,
    const float* __restrict__ skipp, const float* __restrict__ wcv,
    const float* __restrict__ gatel, float* __restrict__ out) {

    // Mld/tld share one backing array so the 23 KB ushort staging buffer can
    // legally alias their first 23040 bytes during phase A/B.
    __shared__ __align__(16) float MT[2 * LCAP];
    __shared__ unsigned int ev[LCAP];    // per-edge (m<<16)|v
    __shared__ float xln[NVAR];          // normalized LLRs
    __shared__ float S[NVAR];            // per-variable message sum
    __shared__ float pooled[NVAR];       // weighted pooled posterior
    __shared__ float Prow[MCHK];         // per-row tanh product
    __shared__ int   rcnt[MCHK];
    __shared__ int   roff[MCHK];
    __shared__ float red[16];
    __shared__ int   wsumI[16];
    __shared__ float scal;
    __shared__ int   EtotS;

    float* const Mld = MT;
    float* const tld = MT + LCAP;
    unsigned short* const stage = (unsigned short*)MT;   // [MCHK][CAP] ushort

    const int b    = blockIdx.x;
    const int tid  = threadIdx.x;
    const int wid  = tid >> 6;
    const int lane = tid & 63;

    const float sig  = sigma2[b];
    const float gate = 1.0f / (1.0f + __expf(-gatel[0]));
    const float gbar = 1.0f - gate;
    const float skip = skipp[0];

    // issue the LLR load early so it overlaps the H scan
    float l = 0.0f;
    if (tid < NVAR) l = -4.0f * inp[(size_t)b * NVAR + tid] / sig;

    // ---- Phase A: H scan -> staged per-row edge lists in LDS ----
    const float* Hb = H + (size_t)b * (MCHK * NVAR);
    for (int m = wid; m < MCHK; m += 16) {
        const float* hrow = Hb + (size_t)m * NVAR;
        const float4* h4  = (const float4*)hrow;
        float4 a  = h4[lane];          // cols 4*lane .. 4*lane+3
        float4 bq = h4[64 + lane];     // cols 256+4*lane ..
        float  c  = hrow[512 + lane];  // col 512+lane
        int cnt = (a.x!=0.f)+(a.y!=0.f)+(a.z!=0.f)+(a.w!=0.f)
                + (bq.x!=0.f)+(bq.y!=0.f)+(bq.z!=0.f)+(bq.w!=0.f) + (c!=0.f);
        int pre = cnt;
        #pragma unroll
        for (int o = 1; o < 64; o <<= 1) {
            int n = __shfl_up(pre, o, 64);
            if (lane >= o) pre += n;
        }
        int p = pre - cnt;                       // exclusive offset in row
        unsigned short* dst = stage + m * CAP;
        int base = lane * 4;
        if (a.x!=0.f)  { if (p<CAP) dst[p] = (unsigned short)(base    ); p++; }
        if (a.y!=0.f)  { if (p<CAP) dst[p] = (unsigned short)(base + 1); p++; }
        if (a.z!=0.f)  { if (p<CAP) dst[p] = (unsigned short)(base + 2); p++; }
        if (a.w!=0.f)  { if (p<CAP) dst[p] = (unsigned short)(base + 3); p++; }
        if (bq.x!=0.f) { if (p<CAP) dst[p] = (unsigned short)(256 + base    ); p++; }
        if (bq.y!=0.f) { if (p<CAP) dst[p] = (unsigned short)(256 + base + 1); p++; }
        if (bq.z!=0.f) { if (p<CAP) dst[p] = (unsigned short)(256 + base + 2); p++; }
        if (bq.w!=0.f) { if (p<CAP) dst[p] = (unsigned short)(256 + base + 3); p++; }
        if (c!=0.f)    { if (p<CAP) dst[p] = (unsigned short)(512 + lane);     p++; }
        if (lane == 63) rcnt[m] = (pre > CAP) ? CAP : pre;
    }
    __syncthreads();

    // ---- Phase B: shfl scan of row counts (waves 0..4 cover 320 slots) ----
    int myc = 0, incl = 0;
    if (tid < 320) {
        myc  = (tid < MCHK) ? rcnt[tid] : 0;
        incl = myc;
        #pragma unroll
        for (int o = 1; o < 64; o <<= 1) {
            int n = __shfl_up(incl, o, 64);
            if (lane >= o) incl += n;
        }
        if (lane == 63) wsumI[wid] = incl;
    }
    __syncthreads();
    if (tid < MCHK) {
        int o = incl - myc;                      // exclusive within wave
        #pragma unroll
        for (int w = 0; w < 4; ++w) if (w < wid) o += wsumI[w];
        int c = myc;
        if (o >= LCAP)         { o = 0; c = 0; }           // defensive
        else if (o + c > LCAP) { c = LCAP - o; }           // defensive
        roff[tid] = o; rcnt[tid] = c;
        const unsigned short* sg = stage + tid * CAP;
        for (int j = 0; j < c; ++j)
            ev[o + j] = ((unsigned)tid << 16) | (unsigned)sg[j];
    }
    if (tid == 0) {
        int e = wsumI[0] + wsumI[1] + wsumI[2] + wsumI[3] + wsumI[4];
        EtotS = (e > LCAP) ? LCAP : e;
    }
    __syncthreads();           // stage reads done; Mld may now clobber it
    const int E = EtotS;

    // ---- LLR normalization + state init ----
    float al = (tid < NVAR) ? fabsf(l) : 0.0f;
    #pragma unroll
    for (int o = 32; o; o >>= 1) al += __shfl_down(al, o, 64);
    if (lane == 0) red[wid] = al;
    for (int e = tid; e < E; e += TPB) Mld[e] = 0.0f;
    if (tid < NVAR) { S[tid] = 0.0f; pooled[tid] = 0.0f; }
    __syncthreads();
    if (tid == 0) {
        float s = 0.0f;
        #pragma unroll
        for (int i = 0; i < 16; ++i) s += red[i];
        scal = (float)NVAR / s;          // 1 / mean|llr|
    }
    __syncthreads();
    if (tid < NVAR) xln[tid] = l * scal;
    __syncthreads();

    float ipl[NITER], opl[NITER];
    #pragma unroll
    for (int t = 0; t < NITER; ++t) { ipl[t] = ipond[t]; opl[t] = opond[t]; }

    // ---- Phase C: 5 BP iterations (numerics identical to prior kernel) ----
    for (int t = 0; t < NITER; ++t) {
        const float pt = ipl[t], ot = opl[t];

        // pass 1: per-edge tanh(0.5*clip(V))
        for (int e = tid; e < E; e += TPB) {
            int v   = (int)(ev[e] & 0xFFFFu);
            float V = fmaf(pt, xln[v], S[v]) - Mld[e];
            V = fminf(15.0f, fmaxf(-15.0f, V));
            float ex = __expf(V);
            float te = (ex - 1.0f) * __builtin_amdgcn_rcpf(ex + 1.0f);
            float x  = 0.5f * V, x2 = x * x;
            float tp = x * fmaf(x2, fmaf(x2, fmaf(x2, -0.05396825f, 0.13333333f),
                                         -0.33333333f), 1.0f);
            tld[e] = (fabsf(V) < 0.5f) ? tp : te;
        }
        __syncthreads();

        // row products; zero S for re-accumulation
        if (tid < MCHK) {
            int c = rcnt[tid], o = roff[tid];
            float P = 1.0f;
            for (int j = 0; j < c; ++j) P *= tld[o + j];
            Prow[tid] = P;
        }
        if (tid < NVAR) S[tid] = 0.0f;
        __syncthreads();

        // pass 2: per-edge c2v message + gated update + scatter
        for (int e = tid; e < E; e += TPB) {
            unsigned pk = ev[e];
            int v = (int)(pk & 0xFFFFu);
            int m = (int)(pk >> 16);
            float tj = tld[e];
            float ts = (fabsf(tj) < 1e-7f) ? ((tj >= 0.0f) ? 1e-7f : -1e-7f) : tj;
            float r  = Prow[m] * __builtin_amdgcn_rcpf(ts);
            r = fminf(1.0f - 1e-6f, fmaxf(-1.0f + 1e-6f, r));
            float w  = wcv[m * NVAR + v];
            float Mn = __logf((1.0f + r) * __builtin_amdgcn_rcpf(1.0f - r)) * w;
            float Mo = fmaf(gate, Mn, gbar * Mld[e]);
            Mld[e] = Mo;
            atomicAdd(&S[v], Mo);
        }
        __syncthreads();

        // posterior normalization + pooled accumulation
        float post = 0.0f, ap = 0.0f;
        if (tid < NVAR) { post = fmaf(pt, xln[tid], S[tid]); ap = fabsf(post); }
        #pragma unroll
        for (int o = 32; o; o >>= 1) ap += __shfl_down(ap, o, 64);
        if (lane == 0) red[wid] = ap;
        __syncthreads();
        if (tid == 0) {
            float s2 = 0.0f;
            #pragma unroll
            for (int i = 0; i < 16; ++i) s2 += red[i];
            scal = (float)NVAR / s2;
        }
        __syncthreads();
        if (tid < NVAR) pooled[tid] += ot * post * scal;
        // no trailing barrier needed: next pass1 only reads S/Mld/xln (all
        // quiesced by the barriers above) and writes tld (not read here).
    }

    // ---- out = pooled/T + skip*norm_llrs ; sigmoid(-out[:, :K]) ----
    if (tid < KINFO) {
        float o = pooled[tid] * (1.0f / NITER) + skip * xln[tid];
        out[(size_t)b * KINFO + tid] = 1.0f / (1.0f + __expf(o));
    }
}

extern "C" void kernel_launch(void* const* d_in, const int* in_sizes, int n_in,
                              void* d_out, int out_size, void* d_ws, size_t ws_size,
                              hipStream_t stream) {
    const float* inp    = (const float*)d_in[0];
    const float* H      = (const float*)d_in[1];
    const float* sigma2 = (const float*)d_in[2];
    const float* ipond  = (const float*)d_in[3];
    const float* opond  = (const float*)d_in[4];
    const float* skipp  = (const float*)d_in[5];
    const float* wcv    = (const float*)d_in[6];
    const float* gatel  = (const float*)d_in[7];
    float* out = (float*)d_out;

    decode<<<B_SZ, TPB, 0, stream>>>(inp, H, sigma2, ipond, opond, skipp,
                                     wcv, gatel, out);
}

// Round 2
// 170.499 us; speedup vs baseline: 1.0393x; 1.0393x over previous
//
#include <hip/hip_runtime.h>

#define B_SZ 128
#define MCHK 288
#define NVAR 576
#define KINFO 288
#define NITER 5
#define CAP 40      // max edges per check row (mean 11.5, 8.5 sigma headroom)
#define LCAP 3712   // max edges per batch element (mean 3318, 6.9 sigma)
#define TPB 1024
#define EPT 4       // max edges per thread: LCAP <= EPT*TPB

// ---------------------------------------------------------------------------
// Fused kernel, one 1024-thread block per batch element.
//  Phase A: H scan (float4, 2-deep software prefetch for MLP), per-row edge
//           lists staged in LDS. Same per-lane emission order as before ->
//           identical edge order -> identical rounding.
//  Phase B: shfl scan of row counts, compact into packed ev[] list.
//  B2:      per-thread edge state moves to REGISTERS: ev, Mld (state), wcv
//           (loop-invariant gather done once). Mld never touches LDS.
//  Phase C: 5 BP iterations. pass2 reuses pass1's t from a register; only
//           tld (for the row product) remains as per-edge LDS traffic.
// All FP reduction/product orders identical to the previous version.
// ---------------------------------------------------------------------------
__global__ __launch_bounds__(TPB) void decode(
    const float* __restrict__ inp,   const float* __restrict__ H,
    const float* __restrict__ sigma2,
    const float* __restrict__ ipond, const float* __restrict__ opond,
    const float* __restrict__ skipp, const float* __restrict__ wcv,
    const float* __restrict__ gatel, float* __restrict__ out) {

    // tld (per-edge tanh, LCAP*4 = 14848 B) aliases the Phase-A ushort
    // staging buffer (MCHK*CAP*2 = 23040 B); union sized to the larger.
    __shared__ __align__(16) float MT[(MCHK * CAP) / 2];   // 23040 B
    __shared__ unsigned int ev[LCAP];    // per-edge (m<<16)|v
    __shared__ float xln[NVAR];          // normalized LLRs
    __shared__ float S[NVAR];            // per-variable message sum
    __shared__ float pooled[NVAR];       // weighted pooled posterior
    __shared__ float Prow[MCHK];         // per-row tanh product
    __shared__ int   rcnt[MCHK];
    __shared__ int   roff[MCHK];
    __shared__ float red[16];
    __shared__ int   wsumI[16];
    __shared__ int   EtotS;

    float* const tld = MT;
    unsigned short* const stage = (unsigned short*)MT;   // [MCHK][CAP]

    const int b    = blockIdx.x;
    const int tid  = threadIdx.x;
    const int wid  = tid >> 6;
    const int lane = tid & 63;

    const float sig  = sigma2[b];
    const float gate = 1.0f / (1.0f + __expf(-gatel[0]));
    const float gbar = 1.0f - gate;
    const float skip = skipp[0];

    float ipl[NITER], opl[NITER];
    #pragma unroll
    for (int t = 0; t < NITER; ++t) { ipl[t] = ipond[t]; opl[t] = opond[t]; }

    // ---- LLR load + |llr| wave reduction (registers only; red covered by
    //      the Phase-A barrier) ----
    float l = 0.0f;
    if (tid < NVAR) l = -4.0f * inp[(size_t)b * NVAR + tid] / sig;
    float al = (tid < NVAR) ? fabsf(l) : 0.0f;
    #pragma unroll
    for (int o = 32; o; o >>= 1) al += __shfl_down(al, o, 64);
    if (lane == 0) red[wid] = al;

    // ---- Phase A: H scan -> staged per-row edge lists in LDS ----
    {
        const float* Hb = H + (size_t)b * (MCHK * NVAR);
        const float* hr0 = Hb + (size_t)wid * NVAR;
        float4 a  = ((const float4*)hr0)[lane];       // cols 4*lane..
        float4 bq = ((const float4*)hr0)[64 + lane];  // cols 256+4*lane..
        float  hc = hr0[512 + lane];                  // col 512+lane
        for (int m = wid; m < MCHK; m += 16) {
            // prefetch next row before doing this row's scan/store work
            const int mn = m + 16;
            float4 na = a, nbq = bq; float nhc = hc;
            if (mn < MCHK) {
                const float* hr = Hb + (size_t)mn * NVAR;
                na  = ((const float4*)hr)[lane];
                nbq = ((const float4*)hr)[64 + lane];
                nhc = hr[512 + lane];
            }
            int cnt = (a.x!=0.f)+(a.y!=0.f)+(a.z!=0.f)+(a.w!=0.f)
                    + (bq.x!=0.f)+(bq.y!=0.f)+(bq.z!=0.f)+(bq.w!=0.f) + (hc!=0.f);
            int pre = cnt;
            #pragma unroll
            for (int o = 1; o < 64; o <<= 1) {
                int n = __shfl_up(pre, o, 64);
                if (lane >= o) pre += n;
            }
            int p = pre - cnt;                       // exclusive offset in row
            unsigned short* dst = stage + m * CAP;
            int base = lane * 4;
            if (a.x!=0.f)  { if (p<CAP) dst[p] = (unsigned short)(base    ); p++; }
            if (a.y!=0.f)  { if (p<CAP) dst[p] = (unsigned short)(base + 1); p++; }
            if (a.z!=0.f)  { if (p<CAP) dst[p] = (unsigned short)(base + 2); p++; }
            if (a.w!=0.f)  { if (p<CAP) dst[p] = (unsigned short)(base + 3); p++; }
            if (bq.x!=0.f) { if (p<CAP) dst[p] = (unsigned short)(256 + base    ); p++; }
            if (bq.y!=0.f) { if (p<CAP) dst[p] = (unsigned short)(256 + base + 1); p++; }
            if (bq.z!=0.f) { if (p<CAP) dst[p] = (unsigned short)(256 + base + 2); p++; }
            if (bq.w!=0.f) { if (p<CAP) dst[p] = (unsigned short)(256 + base + 3); p++; }
            if (hc!=0.f)   { if (p<CAP) dst[p] = (unsigned short)(512 + lane);     p++; }
            if (lane == 63) rcnt[m] = (pre > CAP) ? CAP : pre;
            a = na; bq = nbq; hc = nhc;
        }
    }
    __syncthreads();

    // ---- Phase B: shfl scan of row counts (waves 0..4 cover 320 slots) ----
    int myc = 0, incl = 0;
    if (tid < 320) {
        myc  = (tid < MCHK) ? rcnt[tid] : 0;
        incl = myc;
        #pragma unroll
        for (int o = 1; o < 64; o <<= 1) {
            int n = __shfl_up(incl, o, 64);
            if (lane >= o) incl += n;
        }
        if (lane == 63) wsumI[wid] = incl;
    }
    __syncthreads();
    if (tid < MCHK) {
        int o = incl - myc;                      // exclusive within wave
        #pragma unroll
        for (int w = 0; w < 4; ++w) if (w < wid) o += wsumI[w];
        int c = myc;
        if (o >= LCAP)         { o = 0; c = 0; }           // defensive
        else if (o + c > LCAP) { c = LCAP - o; }           // defensive
        roff[tid] = o; rcnt[tid] = c;
        const unsigned short* sg = stage + tid * CAP;
        for (int j = 0; j < c; ++j)
            ev[o + j] = ((unsigned)tid << 16) | (unsigned)sg[j];
    }
    if (tid < NVAR) { S[tid] = 0.0f; pooled[tid] = 0.0f; }
    if (tid == 0) {
        int e = wsumI[0] + wsumI[1] + wsumI[2] + wsumI[3] + wsumI[4];
        EtotS = (e > LCAP) ? LCAP : e;
    }
    __syncthreads();           // stage reads done; tld may now clobber it
    const int E = EtotS;

    // ---- B2: normalization scale (every thread, same summation order as
    //      the old tid==0 loop -> bit-identical), xln write, and per-thread
    //      edge state into registers ----
    {
        float s = 0.0f;
        #pragma unroll
        for (int i = 0; i < 16; ++i) s += red[i];
        const float sc = (float)NVAR / s;        // 1 / mean|llr|
        if (tid < NVAR) xln[tid] = l * sc;
    }
    unsigned evr[EPT]; float wre[EPT], Ml[EPT], tre[EPT];
    #pragma unroll
    for (int k = 0; k < EPT; ++k) {
        evr[k] = 0u; wre[k] = 0.0f; Ml[k] = 0.0f; tre[k] = 0.0f;
        const int e = tid + k * TPB;
        if (e < E) {
            const unsigned pk = ev[e];
            evr[k] = pk;
            wre[k] = wcv[(pk >> 16) * NVAR + (pk & 0xFFFFu)];
        }
    }
    __syncthreads();           // xln visible to all

    // ---- Phase C: 5 BP iterations ----
    for (int t = 0; t < NITER; ++t) {
        const float pt = ipl[t], ot = opl[t];

        // pass 1: per-edge tanh(0.5*clip(V)); t kept in a register for pass2
        #pragma unroll
        for (int k = 0; k < EPT; ++k) {
            const int e = tid + k * TPB;
            if (e < E) {
                const int v = (int)(evr[k] & 0xFFFFu);
                float V = fmaf(pt, xln[v], S[v]) - Ml[k];
                V = fminf(15.0f, fmaxf(-15.0f, V));
                float ex = __expf(V);
                float te = (ex - 1.0f) * __builtin_amdgcn_rcpf(ex + 1.0f);
                float x  = 0.5f * V, x2 = x * x;
                float tp = x * fmaf(x2, fmaf(x2, fmaf(x2, -0.05396825f, 0.13333333f),
                                             -0.33333333f), 1.0f);
                const float tv = (fabsf(V) < 0.5f) ? tp : te;
                tre[k] = tv;
                tld[e] = tv;
            }
        }
        __syncthreads();

        // row products (2-deep prefetch; multiply order unchanged);
        // zero S for re-accumulation
        if (tid < MCHK) {
            const int c = rcnt[tid], o = roff[tid];
            float P = 1.0f;
            if (c > 0) {
                float cur = tld[o];
                for (int j = 1; j < c; ++j) {
                    const float nx = tld[o + j];
                    P *= cur;
                    cur = nx;
                }
                P *= cur;
            }
            Prow[tid] = P;
        }
        if (tid < NVAR) S[tid] = 0.0f;
        __syncthreads();

        // pass 2: c2v message from registers + gated update + scatter
        #pragma unroll
        for (int k = 0; k < EPT; ++k) {
            const int e = tid + k * TPB;
            if (e < E) {
                const unsigned pk = evr[k];
                const int v = (int)(pk & 0xFFFFu);
                const int m = (int)(pk >> 16);
                const float tj = tre[k];
                const float ts = (fabsf(tj) < 1e-7f) ? ((tj >= 0.0f) ? 1e-7f : -1e-7f) : tj;
                float r = Prow[m] * __builtin_amdgcn_rcpf(ts);
                r = fminf(1.0f - 1e-6f, fmaxf(-1.0f + 1e-6f, r));
                const float Mn = __logf((1.0f + r) * __builtin_amdgcn_rcpf(1.0f - r)) * wre[k];
                const float Mo = fmaf(gate, Mn, gbar * Ml[k]);
                Ml[k] = Mo;
                atomicAdd(&S[v], Mo);
            }
        }
        __syncthreads();

        // posterior normalization + pooled accumulation (per-thread sum of
        // red in the same fixed order -> identical scal, one fewer barrier)
        float post = 0.0f, ap = 0.0f;
        if (tid < NVAR) { post = fmaf(pt, xln[tid], S[tid]); ap = fabsf(post); }
        #pragma unroll
        for (int o = 32; o; o >>= 1) ap += __shfl_down(ap, o, 64);
        if (lane == 0) red[wid] = ap;
        __syncthreads();
        float s2 = 0.0f;
        #pragma unroll
        for (int i = 0; i < 16; ++i) s2 += red[i];
        if (tid < NVAR) pooled[tid] += ot * post * ((float)NVAR / s2);
        // no trailing barrier: next pass1 reads S/xln (quiesced above) and
        // writes tld (last read two barriers ago); red is next written
        // three barriers from now.
    }

    // ---- out = pooled/T + skip*norm_llrs ; sigmoid(-out[:, :K]) ----
    if (tid < KINFO) {
        float o = pooled[tid] * (1.0f / NITER) + skip * xln[tid];
        out[(size_t)b * KINFO + tid] = 1.0f / (1.0f + __expf(o));
    }
}

extern "C" void kernel_launch(void* const* d_in, const int* in_sizes, int n_in,
                              void* d_out, int out_size, void* d_ws, size_t ws_size,
                              hipStream_t stream) {
    const float* inp    = (const float*)d_in[0];
    const float* H      = (const float*)d_in[1];
    const float* sigma2 = (const float*)d_in[2];
    const float* ipond  = (const float*)d_in[3];
    const float* opond  = (const float*)d_in[4];
    const float* skipp  = (const float*)d_in[5];
    const float* wcv    = (const float*)d_in[6];
    const float* gatel  = (const float*)d_in[7];
    float* out = (float*)d_out;

    decode<<<B_SZ, TPB, 0, stream>>>(inp, H, sigma2, ipond, opond, skipp,
                                     wcv, gatel, out);
}